// Round 8
// baseline (968.533 us; speedup 1.0000x reference)
//
#include <hip/hip_runtime.h>
#include <hip/hip_bf16.h>

typedef unsigned short u16;
typedef short s16x8 __attribute__((ext_vector_type(8)));
typedef float f32x4 __attribute__((ext_vector_type(4)));
typedef int   i32x4 __attribute__((ext_vector_type(4)));
typedef u16   u16x4 __attribute__((ext_vector_type(4)));
typedef unsigned int u32;
typedef u32   u32x2 __attribute__((ext_vector_type(2)));

#define HEADS  24
#define HD     128
#define HIDDEN 3072
#define MLPD   12288
#define NTOK   2304
#define SIMG   2048
#define NEMB   9216
#define CATD   15360   // HIDDEN + MLPD
#define QKVD   9216    // 3*HIDDEN
#define FUSEN  21504   // QKVD + MLPD
#define LN_EPS 1e-6f
#define MB     9       // 2304/256 M-blocks

__device__ __forceinline__ u16 f2us(float f){
  __hip_bfloat16 h = __float2bfloat16(f);
  return *reinterpret_cast<u16*>(&h);
}
__device__ __forceinline__ float us2f(u16 u){
  __hip_bfloat16 h;
  *reinterpret_cast<u16*>(&h) = u;
  return __bfloat162float(h);
}
__device__ __forceinline__ float gelu_tanh(float x){
  float y = 0.7978845608028654f*(x + 0.044715f*x*x*x);
  y = fminf(fmaxf(y, -12.f), 12.f);
  float e = __expf(-2.f*y);
  float t = (1.f - e) / (1.f + e);
  return 0.5f*x*(1.0f + t);
}
__device__ __forceinline__ void gload16(const u16* g, u16* l){
  __builtin_amdgcn_global_load_lds(
      (const __attribute__((address_space(1))) void*)g,
      (__attribute__((address_space(3))) void*)l, 16, 0, 0);
}
#define BAR() do{ asm volatile("":::"memory"); __builtin_amdgcn_s_barrier(); asm volatile("":::"memory"); }while(0)
#define LGKM0() asm volatile("s_waitcnt lgkmcnt(0)":::"memory")
#define VMW_(n) asm volatile("s_waitcnt vmcnt(" #n ")":::"memory")
#define VMW(n) VMW_(n)

// ---------------------------------------------------------------- emb kernels
__global__ __launch_bounds__(256)
void emb_partial(const float* __restrict__ temb, const float* __restrict__ wn,
                 float* __restrict__ partial)
{
  __shared__ float ls[384];
  int tid = threadIdx.x;
  int kb = blockIdx.y * 384;
  for (int i = tid; i < 384; i += 256){
    float t = temb[kb + i];
    ls[i] = t / (1.0f + __expf(-t));
  }
  __syncthreads();
  int j = blockIdx.x*256 + tid;
  const float* wp = wn + (size_t)kb*NEMB + j;
  float acc = 0.f;
  #pragma unroll 8
  for (int i = 0; i < 384; i++){ acc = fmaf(ls[i], wp[0], acc); wp += NEMB; }
  partial[blockIdx.y*NEMB + j] = acc;
}

__global__ __launch_bounds__(256)
void emb_reduce(const float* __restrict__ partial, const float* __restrict__ bn,
                float* __restrict__ emb)
{
  int j = blockIdx.x*256 + threadIdx.x;
  float s = bn[j];
  #pragma unroll
  for (int r = 0; r < 8; r++) s += partial[r*NEMB + j];
  emb[j] = s;
}

// ------------------------------------------------- layernorm + modulate (bf16)
__global__ __launch_bounds__(256)
void ln_mod(const float* __restrict__ hs, const float* __restrict__ ehs,
            const float* __restrict__ emb, u16* __restrict__ nx)
{
  int row = blockIdx.x;
  const float* x = (row < SIMG) ? hs + (size_t)row*HIDDEN
                                : ehs + (size_t)(row - SIMG)*HIDDEN;
  int tid = threadIdx.x;
  float vals[12];
  float s = 0.f, ss = 0.f;
  #pragma unroll
  for (int i = 0; i < 3; i++){
    float4 v = *reinterpret_cast<const float4*>(x + i*1024 + tid*4);
    vals[i*4+0]=v.x; vals[i*4+1]=v.y; vals[i*4+2]=v.z; vals[i*4+3]=v.w;
    s += v.x+v.y+v.z+v.w;
    ss += v.x*v.x + v.y*v.y + v.z*v.z + v.w*v.w;
  }
  #pragma unroll
  for (int d = 1; d < 64; d <<= 1){ s += __shfl_xor(s, d); ss += __shfl_xor(ss, d); }
  __shared__ float red[8];
  if ((tid & 63) == 0){ red[tid>>6] = s; red[4 + (tid>>6)] = ss; }
  __syncthreads();
  s  = red[0]+red[1]+red[2]+red[3];
  ss = red[4]+red[5]+red[6]+red[7];
  float mu = s * (1.0f/HIDDEN);
  float var = ss * (1.0f/HIDDEN) - mu*mu;
  float rs = rsqrtf(var + LN_EPS);
  #pragma unroll
  for (int i = 0; i < 3; i++){
    int col = i*1024 + tid*4;
    u16x4 o;
    #pragma unroll
    for (int j = 0; j < 4; j++){
      float nv = (vals[i*4+j] - mu) * rs;
      float outv = nv * (1.0f + emb[HIDDEN + col + j]) + emb[col + j];
      o[j] = f2us(outv);
    }
    *reinterpret_cast<u16x4*>(nx + (size_t)row*HIDDEN + col) = o;
  }
}

// ------------------------------------------- W[K][N] f32 -> Wt[noff+n][k] bf16
__global__ __launch_bounds__(256)
void transpose_w(const float* __restrict__ W, u16* __restrict__ Wt,
                 int K, int N, int ldt, int noff)
{
  __shared__ float t[64][65];
  const int tid = threadIdx.x;
  const int kb = blockIdx.y * 64, nb = blockIdx.x * 64;
  #pragma unroll
  for (int i = 0; i < 4; i++){
    int row = (tid >> 4) + i*16;
    int c4  = (tid & 15) * 4;
    float4 v = *reinterpret_cast<const float4*>(W + (size_t)(kb+row)*N + nb + c4);
    t[row][c4] = v.x; t[row][c4+1] = v.y; t[row][c4+2] = v.z; t[row][c4+3] = v.w;
  }
  __syncthreads();
  int n  = tid >> 2;
  int kc = (tid & 3) * 16;
  u16 tmp[16];
  #pragma unroll
  for (int j = 0; j < 16; j++) tmp[j] = f2us(t[kc+j][n]);
  u16* dst = Wt + (size_t)(noff + nb + n)*ldt + kb + kc;
  *reinterpret_cast<i32x4*>(dst)     = *reinterpret_cast<const i32x4*>(tmp);
  *reinterpret_cast<i32x4*>(dst + 8) = *reinterpret_cast<const i32x4*>(tmp + 8);
}

// ---------------------------------------------- deep-pipelined 256² GEMM (v8)
// Identical region/vmcnt ledger to round 7, ONE change: no lgkmcnt(0) +
// sched_barrier pin between ds_reads and MFMAs. The compiler emits
// fine-grained lgkmcnt(N) so MFMA group g runs while reads g+1.. are still
// in flight -> LDS port and matrix pipe overlap (they were strictly
// serialized: 2313 + 2483 cyc per K-tile = measured 5760). lgkmcnt(0) before
// each phase-ending barrier keeps the region-overwrite ledger exact.
template<int EPI>
__global__ __launch_bounds__(512, 2)
void gemm8(const u16* __restrict__ A_, int lda,
           const u16* __restrict__ Bt_, int ldb,
           int K, int N, int kspl,
           const float* __restrict__ b0, const float* __restrict__ b1,
           const float* __restrict__ b2, const float* __restrict__ b3,
           u16* __restrict__ qkvo, u16* __restrict__ hcat,
           float* __restrict__ outf)
{
  extern __shared__ __align__(16) u16 lds[];   // 65536 u16 = 128 KiB
  const int tid = threadIdx.x, lane = tid & 63, wid = tid >> 6;
  const int l15 = lane & 15, lhi = lane >> 4;
  const int wm = wid >> 2, wn = wid & 3;
  const int NKH = K / 32;   // K-halves; must be %8==0 and >=16

  const u16* Ag = A_  + (size_t)blockIdx.z * kspl;
  const u16* Bg = Bt_ + (size_t)blockIdx.z * kspl;

  // bijective XCD-aware swizzle (m204), column-major block order
  const int nwg = gridDim.x;
  int orig = blockIdx.x;
  int qq = nwg >> 3, rr = nwg & 7;
  int xcd = orig & 7, loc = orig >> 3;
  int wg = (xcd < rr ? xcd*(qq+1) : rr*(qq+1) + (xcd-rr)*qq) + loc;
  const int m0 = (wg % MB) * 256;
  const int n0 = (wg / MB) * 256;

  // staging global pointers (2 issues per 16KB region per wave: A0/A1, B0/B1)
  const u16 *gA0, *gA1, *gB0, *gB1;
  {
    size_t offA[2], offB[2];
    #pragma unroll
    for (int q = 0; q < 2; q++){
      int Lb = q*8192 + tid*16;          // byte offset within region
      int r  = Lb >> 7;                  // LDS row (128B rows)
      int gp = (Lb >> 4) & 7;
      int g  = gp ^ (r & 7);
      int row = 2*r + (g >> 2);
      int ke  = (g & 3) * 8;
      offA[q] = (size_t)(m0 + row)*lda + ke;
      offB[q] = (size_t)(n0 + row)*ldb + ke;
    }
    gA0 = Ag + offA[0]; gA1 = Ag + offA[1];
    gB0 = Bg + offB[0]; gB1 = Bg + offB[1];
  }
  u16* dA0 = lds + tid*8;
  u16* dA1 = lds + 4096 + tid*8;
  u16* dB0 = lds + 32768 + tid*8;
  u16* dB1 = lds + 36864 + tid*8;

  // per-lane LDS read bases; fragment deltas are compile-time immediates
  const char *pa0, *pb0;
  {
    const char* LB = (const char*)lds;
    int Ra = wm*128 + l15;
    pa0 = LB + (Ra>>1)*128 + (((((Ra&1)<<2)|lhi) ^ ((Ra>>1)&7))*16);
    int Rb = wn*64 + l15;
    pb0 = LB + 65536 + (Rb>>1)*128 + (((((Rb&1)<<2)|lhi) ^ ((Rb>>1)&7))*16);
  }

  f32x4 acc[8][4];
  #pragma unroll
  for (int i = 0; i < 8; i++)
    #pragma unroll
    for (int j = 0; j < 4; j++){ f32x4 z = {0.f,0.f,0.f,0.f}; acc[i][j] = z; }

  #define LD8(P_) (*reinterpret_cast<const s16x8*>(P_))
  #define MFMA_ALL(AF_, BF_) do{                                               \
    _Pragma("unroll") for (int a_=0;a_<8;a_++)                                 \
      _Pragma("unroll") for (int nf_=0;nf_<4;nf_++)                            \
        acc[a_][nf_] = __builtin_amdgcn_mfma_f32_16x16x32_bf16(                \
            (AF_)[a_], (BF_)[nf_], acc[a_][nf_], 0, 0, 0); }while(0)

  // RP_: read region (0-3). SP_: stage region. DOI_: do stage. GOFF_: global
  // elem offset of staged half. VN_: vmcnt before phase-ending barrier.
  // Read order: af[0], bf[0..3], af[1..7] -> first MFMA quad unblocks after
  // 5 in-order DS returns (compiler emits counted lgkmcnt, NOT drained).
  #define PHASEP(RP_,SP_,DOI_,GOFF_,VN_) do{                                   \
    s16x8 af[8], bf[4];                                                        \
    af[0] = LD8(pa0 + (RP_)*16384);                                            \
    _Pragma("unroll") for (int i_=0;i_<4;i_++)                                 \
      bf[i_] = LD8(pb0 + (RP_)*16384 + i_*1024);                               \
    _Pragma("unroll") for (int i_=1;i_<8;i_++)                                 \
      af[i_] = LD8(pa0 + (RP_)*16384 + (i_>>2)*4096 + (i_&3)*1024);            \
    if (DOI_){                                                                 \
      gload16(gA0+(GOFF_), dA0+(SP_)*8192); gload16(gA1+(GOFF_), dA1+(SP_)*8192);\
      gload16(gB0+(GOFF_), dB0+(SP_)*8192); gload16(gB1+(GOFF_), dB1+(SP_)*8192);\
    }                                                                          \
    __builtin_amdgcn_s_setprio(1);                                             \
    MFMA_ALL(af, bf);                                                          \
    __builtin_amdgcn_s_setprio(0);                                             \
    LGKM0();                                                                   \
    VMW(VN_);                                                                  \
    BAR();                                                                     \
  }while(0)

  // prologue: stage halves 0,1,2 -> regions 0,1,2 (12 loads, 3 groups)
  gload16(gA0,    dA0);        gload16(gA1,    dA1);
  gload16(gB0,    dB0);        gload16(gB1,    dB1);
  gload16(gA0+32, dA0+8192);   gload16(gA1+32, dA1+8192);
  gload16(gB0+32, dB0+8192);   gload16(gB1+32, dB1+8192);
  gload16(gA0+64, dA0+16384);  gload16(gA1+64, dA1+16384);
  gload16(gB0+64, dB0+16384);  gload16(gB1+64, dB1+16384);
  VMW(8);   // region 0 landed
  BAR();

  const int nblk = NKH >> 3;
  for (int b = 0; b < nblk - 1; b++){
    PHASEP(0,3,1, 96,8); PHASEP(1,0,1,128,8); PHASEP(2,1,1,160,8); PHASEP(3,2,1,192,8);
    PHASEP(0,3,1,224,8); PHASEP(1,0,1,256,8); PHASEP(2,1,1,288,8); PHASEP(3,2,1,320,8);
    gA0 += 256; gA1 += 256; gB0 += 256; gB1 += 256;
  }
  // final 8-phase block: stages end at local phase 4; end-of-phase drains 4,0
  PHASEP(0,3,1, 96,8); PHASEP(1,0,1,128,8); PHASEP(2,1,1,160,8); PHASEP(3,2,1,192,8);
  PHASEP(0,3,1,224,8); PHASEP(1,0,0,  0,4); PHASEP(2,1,0,  0,0); PHASEP(3,2,0,  0,0);

  #undef PHASEP
  #undef MFMA_ALL
  #undef LD8

  // epilogue
  #pragma unroll
  for (int a = 0; a < 8; a++){
    #pragma unroll
    for (int nf = 0; nf < 4; nf++){
      int col = n0 + wn*64 + nf*16 + l15;
      #pragma unroll
      for (int r = 0; r < 4; r++){
        int row = m0 + wm*128 + a*16 + lhi*4 + r;
        float v = acc[a][nf][r];
        if constexpr (EPI == 0){
          if (col < QKVD){
            const float* bp = b0; int c = col;
            if (c >= 6144){ bp = b2; c -= 6144; }
            else if (c >= 3072){ bp = b1; c -= 3072; }
            qkvo[(size_t)row*QKVD + col] = f2us(v + bp[c]);
          } else {
            int c2 = col - QKVD;
            hcat[(size_t)row*CATD + HIDDEN + c2] = f2us(gelu_tanh(v + b3[c2]));
          }
        } else {
          outf[(size_t)blockIdx.z*NTOK*HIDDEN + (size_t)row*HIDDEN + col] = v;
        }
      }
    }
  }
}

// ------------------------------------- split-K reduce + gate/residual epilogue
__global__ __launch_bounds__(256)
void reduce_out(const float* __restrict__ part, const float* __restrict__ bout,
                const float* __restrict__ emb,
                const float* __restrict__ hs, const float* __restrict__ ehs,
                float* __restrict__ outp)
{
  int row = blockIdx.x;
  const float* res = (row < SIMG) ? hs + (size_t)row*HIDDEN
                                  : ehs + (size_t)(row - SIMG)*HIDDEN;
  #pragma unroll
  for (int i = 0; i < 3; i++){
    int col = i*1024 + threadIdx.x*4;
    float4 a = *reinterpret_cast<const float4*>(part + (size_t)row*HIDDEN + col);
    float4 b = *reinterpret_cast<const float4*>(part + (size_t)NTOK*HIDDEN + (size_t)row*HIDDEN + col);
    float4 rr = *reinterpret_cast<const float4*>(res + col);
    float4 bb = *reinterpret_cast<const float4*>(bout + col);
    float4 gg = *reinterpret_cast<const float4*>(emb + 2*HIDDEN + col);
    float4 o;
    o.x = gg.x*(a.x+b.x+bb.x) + rr.x;
    o.y = gg.y*(a.y+b.y+bb.y) + rr.y;
    o.z = gg.z*(a.z+b.z+bb.z) + rr.z;
    o.w = gg.w*(a.w+b.w+bb.w) + rr.w;
    *reinterpret_cast<float4*>(outp + (size_t)row*HIDDEN + col) = o;
  }
}

// ------------------------------------------- rmsnorm + rope on q,k (in place)
__global__ __launch_bounds__(256)
void qk_post(u16* __restrict__ qkv,
             const float* __restrict__ nqw, const float* __restrict__ nkw,
             const float* __restrict__ fc)
{
  int rid = blockIdx.x*4 + (threadIdx.x >> 6);
  int lane = threadIdx.x & 63;
  int isK = rid >= NTOK*HEADS;
  int r = isK ? rid - NTOK*HEADS : rid;
  int token = r / HEADS, head = r % HEADS;
  u16* p = qkv + (size_t)token*QKVD + (isK ? HIDDEN : 0) + head*HD + lane*2;
  unsigned int u = *reinterpret_cast<unsigned int*>(p);
  float v0 = us2f((u16)(u & 0xffff));
  float v1 = us2f((u16)(u >> 16));
  float ss = v0*v0 + v1*v1;
  #pragma unroll
  for (int d = 1; d < 64; d <<= 1) ss += __shfl_xor(ss, d);
  float rs = rsqrtf(ss * (1.0f/HD) + LN_EPS);
  const float* wv = isK ? nkw : nqw;
  v0 *= rs * wv[lane*2];
  v1 *= rs * wv[lane*2+1];
  if (token < SIMG){
    const float* f = fc + (size_t)token*(2*HD);
    float c0 = f[lane*2],      c1 = f[lane*2+1];
    float s0 = f[HD + lane*2], s1 = f[HD + lane*2+1];
    float o0 = v0*c0 - v1*s0;
    float o1 = v1*c1 + v0*s1;
    v0 = o0; v1 = o1;
  }
  unsigned int uo = (unsigned int)f2us(v0) | ((unsigned int)f2us(v1) << 16);
  *reinterpret_cast<unsigned int*>(p) = uo;
}

// ------------------------------------------------------------ flash attention
// Q fragments in regs; K/V prefetched one tile ahead into regs (T14);
// V-transpose via packed ds_write_b64.
__global__ __launch_bounds__(256)
void attn_kernel(const u16* __restrict__ qkv, u16* __restrict__ hcat)
{
  __shared__ __align__(16) u16 Qs[64][136];
  __shared__ __align__(16) u16 Ks[64][136];
  __shared__ __align__(16) u16 Vt[128][72];
  __shared__ __align__(16) u16 Ps[64][72];

  const int tid = threadIdx.x, lane = tid & 63, w = tid >> 6;
  const int head = blockIdx.y, qb = blockIdx.x;
  const int l15 = lane & 15, lhi = lane >> 4;
  const int q0 = qb * 64;
  const float scale = 0.08838834764831845f;

  #pragma unroll
  for (int i = 0; i < 4; i++){
    int c = tid + 256*i;
    int row = c >> 4, d0 = (c & 15) * 8;
    i32x4 vv = *reinterpret_cast<const i32x4*>(qkv + (size_t)(q0+row)*QKVD + head*HD + d0);
    *reinterpret_cast<i32x4*>(&Qs[row][d0]) = vv;
  }

  int krow[4], kd0[4];
  #pragma unroll
  for (int i = 0; i < 4; i++){ int c = tid + 256*i; krow[i] = c >> 4; kd0[i] = (c & 15)*8; }
  const int vbase = w*16 + lhi*4;
  const int vd0   = l15*8;
  char* vwp = (char*)(&Vt[0][0]) + vd0*144 + (((vbase>>3) ^ ((vd0>>3)&7))*16) + (vbase&7)*2;

  i32x4 kr0, kr1, kr2, kr3, vr0, vr1, vr2, vr3;
  {
    const u16* kbp = qkv + HIDDEN + (size_t)head*HD;
    const u16* vbp = qkv + 2*HIDDEN + (size_t)head*HD;
    kr0 = *reinterpret_cast<const i32x4*>(kbp + (size_t)(krow[0])*QKVD + kd0[0]);
    kr1 = *reinterpret_cast<const i32x4*>(kbp + (size_t)(krow[1])*QKVD + kd0[1]);
    kr2 = *reinterpret_cast<const i32x4*>(kbp + (size_t)(krow[2])*QKVD + kd0[2]);
    kr3 = *reinterpret_cast<const i32x4*>(kbp + (size_t)(krow[3])*QKVD + kd0[3]);
    vr0 = *reinterpret_cast<const i32x4*>(vbp + (size_t)(vbase+0)*QKVD + vd0);
    vr1 = *reinterpret_cast<const i32x4*>(vbp + (size_t)(vbase+1)*QKVD + vd0);
    vr2 = *reinterpret_cast<const i32x4*>(vbp + (size_t)(vbase+2)*QKVD + vd0);
    vr3 = *reinterpret_cast<const i32x4*>(vbp + (size_t)(vbase+3)*QKVD + vd0);
  }
  __syncthreads();

  s16x8 qf[4];
  #pragma unroll
  for (int ks = 0; ks < 4; ks++)
    qf[ks] = *reinterpret_cast<const s16x8*>(&Qs[w*16 + l15][ks*32 + lhi*8]);

  f32x4 O[8];
  #pragma unroll
  for (int i = 0; i < 8; i++){ f32x4 z = {0.f,0.f,0.f,0.f}; O[i] = z; }
  float mrow[4], lrow[4];
  #pragma unroll
  for (int r = 0; r < 4; r++){ mrow[r] = -1e30f; lrow[r] = 0.f; }

  for (int kv0 = 0; kv0 < NTOK; kv0 += 64){
    *reinterpret_cast<i32x4*>(&Ks[krow[0]][kd0[0]]) = kr0;
    *reinterpret_cast<i32x4*>(&Ks[krow[1]][kd0[1]]) = kr1;
    *reinterpret_cast<i32x4*>(&Ks[krow[2]][kd0[2]]) = kr2;
    *reinterpret_cast<i32x4*>(&Ks[krow[3]][kd0[3]]) = kr3;
    #pragma unroll
    for (int dd = 0; dd < 8; dd++){
      u32 a0 = (u32)(dd & 1 ? ((u32)vr0[dd>>1]) >> 16 : ((u32)vr0[dd>>1]) & 0xffff);
      u32 a1 = (u32)(dd & 1 ? ((u32)vr1[dd>>1]) >> 16 : ((u32)vr1[dd>>1]) & 0xffff);
      u32 a2 = (u32)(dd & 1 ? ((u32)vr2[dd>>1]) >> 16 : ((u32)vr2[dd>>1]) & 0xffff);
      u32 a3 = (u32)(dd & 1 ? ((u32)vr3[dd>>1]) >> 16 : ((u32)vr3[dd>>1]) & 0xffff);
      u32x2 pk; pk[0] = a0 | (a1 << 16); pk[1] = a2 | (a3 << 16);
      *reinterpret_cast<u32x2*>(vwp + dd*144) = pk;
    }
    __syncthreads();

    if (kv0 + 64 < NTOK){
      const u16* kbp = qkv + (size_t)(kv0+64)*QKVD + HIDDEN + (size_t)head*HD;
      const u16* vbp = qkv + (size_t)(kv0+64)*QKVD + 2*HIDDEN + (size_t)head*HD;
      kr0 = *reinterpret_cast<const i32x4*>(kbp + (size_t)(krow[0])*QKVD + kd0[0]);
      kr1 = *reinterpret_cast<const i32x4*>(kbp + (size_t)(krow[1])*QKVD + kd0[1]);
      kr2 = *reinterpret_cast<const i32x4*>(kbp + (size_t)(krow[2])*QKVD + kd0[2]);
      kr3 = *reinterpret_cast<const i32x4*>(kbp + (size_t)(krow[3])*QKVD + kd0[3]);
      vr0 = *reinterpret_cast<const i32x4*>(vbp + (size_t)(vbase+0)*QKVD + vd0);
      vr1 = *reinterpret_cast<const i32x4*>(vbp + (size_t)(vbase+1)*QKVD + vd0);
      vr2 = *reinterpret_cast<const i32x4*>(vbp + (size_t)(vbase+2)*QKVD + vd0);
      vr3 = *reinterpret_cast<const i32x4*>(vbp + (size_t)(vbase+3)*QKVD + vd0);
    }

    f32x4 S[4];
    #pragma unroll
    for (int nf = 0; nf < 4; nf++){ f32x4 z = {0.f,0.f,0.f,0.f}; S[nf] = z; }
    #pragma unroll
    for (int ks = 0; ks < 4; ks++){
      #pragma unroll
      for (int nf = 0; nf < 4; nf++){
        s16x8 b = *reinterpret_cast<const s16x8*>(&Ks[nf*16 + l15][ks*32 + lhi*8]);
        S[nf] = __builtin_amdgcn_mfma_f32_16x16x32_bf16(qf[ks], b, S[nf], 0, 0, 0);
      }
    }
    #pragma unroll
    for (int nf = 0; nf < 4; nf++)
      #pragma unroll
      for (int r = 0; r < 4; r++) S[nf][r] *= scale;

    float fsc[4];
    #pragma unroll
    for (int r = 0; r < 4; r++){
      float mx = -1e30f;
      #pragma unroll
      for (int nf = 0; nf < 4; nf++) mx = fmaxf(mx, S[nf][r]);
      #pragma unroll
      for (int d = 1; d < 16; d <<= 1) mx = fmaxf(mx, __shfl_xor(mx, d));
      float mn = fmaxf(mrow[r], mx);
      float f = __expf(mrow[r] - mn);
      mrow[r] = mn; fsc[r] = f;
      float lsum = 0.f;
      int prow = w*16 + lhi*4 + r;
      #pragma unroll
      for (int nf = 0; nf < 4; nf++){
        float pvl = __expf(S[nf][r] - mn);
        lsum += pvl;
        int pcol = nf*16 + l15;
        int col = (((pcol>>3) ^ (prow&7)) << 3) | (pcol & 7);
        Ps[prow][col] = f2us(pvl);
      }
      #pragma unroll
      for (int d = 1; d < 16; d <<= 1) lsum += __shfl_xor(lsum, d);
      lrow[r] = lrow[r]*f + lsum;
    }
    #pragma unroll
    for (int nf = 0; nf < 8; nf++)
      #pragma unroll
      for (int r = 0; r < 4; r++) O[nf][r] *= fsc[r];

    #pragma unroll
    for (int ks = 0; ks < 2; ks++){
      int prow = w*16 + l15;
      int cb = ((ks*4 + lhi) ^ (prow & 7)) << 3;
      s16x8 a = *reinterpret_cast<const s16x8*>(&Ps[prow][cb]);
      #pragma unroll
      for (int nf = 0; nf < 8; nf++){
        int d = nf*16 + l15;
        int vb = ((ks*4 + lhi) ^ ((d>>3)&7)) << 3;
        s16x8 b = *reinterpret_cast<const s16x8*>(&Vt[d][vb]);
        O[nf] = __builtin_amdgcn_mfma_f32_16x16x32_bf16(a, b, O[nf], 0, 0, 0);
      }
    }
    __syncthreads();
  }

  #pragma unroll
  for (int nf = 0; nf < 8; nf++){
    #pragma unroll
    for (int r = 0; r < 4; r++){
      int row = q0 + w*16 + lhi*4 + r;
      int col = head*HD + nf*16 + l15;
      hcat[(size_t)row*CATD + col] = f2us(O[nf][r] / lrow[r]);
    }
  }
}

// ---------------------------------------------------------------------- host
extern "C" void kernel_launch(void* const* d_in, const int* in_sizes, int n_in,
                              void* d_out, int out_size, void* d_ws, size_t ws_size,
                              hipStream_t stream)
{
  const float* hs    = (const float*)d_in[0];
  const float* ehs   = (const float*)d_in[1];
  const float* temb  = (const float*)d_in[2];
  const float* fc    = (const float*)d_in[3];
  const float* wnorm = (const float*)d_in[4];
  const float* bnorm = (const float*)d_in[5];
  const float* wq    = (const float*)d_in[6];
  const float* bq    = (const float*)d_in[7];
  const float* wk    = (const float*)d_in[8];
  const float* bk    = (const float*)d_in[9];
  const float* wv    = (const float*)d_in[10];
  const float* bv    = (const float*)d_in[11];
  const float* nqw   = (const float*)d_in[12];
  const float* nkw   = (const float*)d_in[13];
  const float* wmlp  = (const float*)d_in[14];
  const float* bmlp  = (const float*)d_in[15];
  const float* wout  = (const float*)d_in[16];
  const float* bout  = (const float*)d_in[17];
  float* outp = (float*)d_out;

  char* ws = (char*)d_ws;
  float* emb  = (float*)ws;                               // 36864 B
  float* part = (float*)(ws + 36864);                     // 294912 B
  u16* nx     = (u16*)(ws + 36864 + 294912);
  u16* qkv    = nx  + (size_t)NTOK*HIDDEN;
  u16* hcat   = qkv + (size_t)NTOK*QKVD;
  u16* Wt     = hcat + (size_t)NTOK*CATD;
  float* partial = (float*)nx;  // aliases nx+qkv (dead by out-proj time)

  hipFuncSetAttribute((const void*)gemm8<0>, hipFuncAttributeMaxDynamicSharedMemorySize, 131072);
  hipFuncSetAttribute((const void*)gemm8<1>, hipFuncAttributeMaxDynamicSharedMemorySize, 131072);

  emb_partial<<<dim3(36,8), 256, 0, stream>>>(temb, wnorm, part);
  emb_reduce<<<36, 256, 0, stream>>>(part, bnorm, emb);
  ln_mod<<<NTOK, 256, 0, stream>>>(hs, ehs, emb, nx);

  transpose_w<<<dim3(48,48), 256, 0, stream>>>(wq,   Wt, HIDDEN, HIDDEN, HIDDEN, 0);
  transpose_w<<<dim3(48,48), 256, 0, stream>>>(wk,   Wt, HIDDEN, HIDDEN, HIDDEN, HIDDEN);
  transpose_w<<<dim3(48,48), 256, 0, stream>>>(wv,   Wt, HIDDEN, HIDDEN, HIDDEN, 2*HIDDEN);
  transpose_w<<<dim3(192,48), 256, 0, stream>>>(wmlp, Wt, HIDDEN, MLPD, HIDDEN, QKVD);

  // fused QKV+MLP GEMM: [2304 x 21504], K=3072 (NKH=96)
  gemm8<0><<<dim3((FUSEN/256)*MB, 1, 1), 512, 131072, stream>>>(
      nx, HIDDEN, Wt, HIDDEN, HIDDEN, FUSEN, 0,
      bq, bk, bv, bmlp, qkv, hcat, nullptr);

  transpose_w<<<dim3(48,240), 256, 0, stream>>>(wout, Wt, CATD, HIDDEN, CATD, 0);

  qk_post<<<(2*NTOK*HEADS)/4, 256, 0, stream>>>(qkv, nqw, nkw, fc);
  attn_kernel<<<dim3(NTOK/64, HEADS), 256, 0, stream>>>(qkv, hcat);

  // out-proj: split-K=2 (NKH=240 each), f32 partials
  gemm8<1><<<dim3((HIDDEN/256)*MB, 1, 2), 512, 131072, stream>>>(
      hcat, CATD, Wt, CATD, CATD/2, HIDDEN, CATD/2,
      nullptr, nullptr, nullptr, nullptr, nullptr, nullptr, partial);

  reduce_out<<<NTOK, 256, 0, stream>>>(partial, bout, emb, hs, ehs, outp);
}

// Round 9
// 952.259 us; speedup vs baseline: 1.0171x; 1.0171x over previous
//
#include <hip/hip_runtime.h>
#include <hip/hip_bf16.h>

typedef unsigned short u16;
typedef short s16x8 __attribute__((ext_vector_type(8)));
typedef float f32x4 __attribute__((ext_vector_type(4)));
typedef int   i32x4 __attribute__((ext_vector_type(4)));
typedef int   i32x2 __attribute__((ext_vector_type(2)));
typedef u16   u16x4 __attribute__((ext_vector_type(4)));
typedef unsigned int u32;
typedef u32   u32x2 __attribute__((ext_vector_type(2)));

#define HEADS  24
#define HD     128
#define HIDDEN 3072
#define MLPD   12288
#define NTOK   2304
#define SIMG   2048
#define NEMB   9216
#define CATD   15360   // HIDDEN + MLPD
#define QKVD   9216    // 3*HIDDEN
#define FUSEN  21504   // QKVD + MLPD
#define LN_EPS 1e-6f
#define MB     9       // 2304/256 M-blocks

__device__ __forceinline__ u16 f2us(float f){
  __hip_bfloat16 h = __float2bfloat16(f);
  return *reinterpret_cast<u16*>(&h);
}
__device__ __forceinline__ float us2f(u16 u){
  __hip_bfloat16 h;
  *reinterpret_cast<u16*>(&h) = u;
  return __bfloat162float(h);
}
__device__ __forceinline__ float gelu_tanh(float x){
  float y = 0.7978845608028654f*(x + 0.044715f*x*x*x);
  y = fminf(fmaxf(y, -12.f), 12.f);
  float e = __expf(-2.f*y);
  float t = (1.f - e) / (1.f + e);
  return 0.5f*x*(1.0f + t);
}
__device__ __forceinline__ void gload16(const u16* g, u16* l){
  __builtin_amdgcn_global_load_lds(
      (const __attribute__((address_space(1))) void*)g,
      (__attribute__((address_space(3))) void*)l, 16, 0, 0);
}
#define BAR() do{ asm volatile("":::"memory"); __builtin_amdgcn_s_barrier(); asm volatile("":::"memory"); }while(0)
#define LGKM0() asm volatile("s_waitcnt lgkmcnt(0)":::"memory")
#define VMW_(n) asm volatile("s_waitcnt vmcnt(" #n ")":::"memory")
#define VMW(n) VMW_(n)

// ---------------------------------------------------------------- emb kernels
__global__ __launch_bounds__(256)
void emb_partial(const float* __restrict__ temb, const float* __restrict__ wn,
                 float* __restrict__ partial)
{
  __shared__ float ls[384];
  int tid = threadIdx.x;
  int kb = blockIdx.y * 384;
  for (int i = tid; i < 384; i += 256){
    float t = temb[kb + i];
    ls[i] = t / (1.0f + __expf(-t));
  }
  __syncthreads();
  int j = blockIdx.x*256 + tid;
  const float* wp = wn + (size_t)kb*NEMB + j;
  float acc = 0.f;
  #pragma unroll 8
  for (int i = 0; i < 384; i++){ acc = fmaf(ls[i], wp[0], acc); wp += NEMB; }
  partial[blockIdx.y*NEMB + j] = acc;
}

__global__ __launch_bounds__(256)
void emb_reduce(const float* __restrict__ partial, const float* __restrict__ bn,
                float* __restrict__ emb)
{
  int j = blockIdx.x*256 + threadIdx.x;
  float s = bn[j];
  #pragma unroll
  for (int r = 0; r < 8; r++) s += partial[r*NEMB + j];
  emb[j] = s;
}

// ------------------------------------------------- layernorm + modulate (bf16)
__global__ __launch_bounds__(256)
void ln_mod(const float* __restrict__ hs, const float* __restrict__ ehs,
            const float* __restrict__ emb, u16* __restrict__ nx)
{
  int row = blockIdx.x;
  const float* x = (row < SIMG) ? hs + (size_t)row*HIDDEN
                                : ehs + (size_t)(row - SIMG)*HIDDEN;
  int tid = threadIdx.x;
  float vals[12];
  float s = 0.f, ss = 0.f;
  #pragma unroll
  for (int i = 0; i < 3; i++){
    float4 v = *reinterpret_cast<const float4*>(x + i*1024 + tid*4);
    vals[i*4+0]=v.x; vals[i*4+1]=v.y; vals[i*4+2]=v.z; vals[i*4+3]=v.w;
    s += v.x+v.y+v.z+v.w;
    ss += v.x*v.x + v.y*v.y + v.z*v.z + v.w*v.w;
  }
  #pragma unroll
  for (int d = 1; d < 64; d <<= 1){ s += __shfl_xor(s, d); ss += __shfl_xor(ss, d); }
  __shared__ float red[8];
  if ((tid & 63) == 0){ red[tid>>6] = s; red[4 + (tid>>6)] = ss; }
  __syncthreads();
  s  = red[0]+red[1]+red[2]+red[3];
  ss = red[4]+red[5]+red[6]+red[7];
  float mu = s * (1.0f/HIDDEN);
  float var = ss * (1.0f/HIDDEN) - mu*mu;
  float rs = rsqrtf(var + LN_EPS);
  #pragma unroll
  for (int i = 0; i < 3; i++){
    int col = i*1024 + tid*4;
    u16x4 o;
    #pragma unroll
    for (int j = 0; j < 4; j++){
      float nv = (vals[i*4+j] - mu) * rs;
      float outv = nv * (1.0f + emb[HIDDEN + col + j]) + emb[col + j];
      o[j] = f2us(outv);
    }
    *reinterpret_cast<u16x4*>(nx + (size_t)row*HIDDEN + col) = o;
  }
}

// ------------------------------------------- W[K][N] f32 -> Wt[noff+n][k] bf16
__global__ __launch_bounds__(256)
void transpose_w(const float* __restrict__ W, u16* __restrict__ Wt,
                 int K, int N, int ldt, int noff)
{
  __shared__ float t[64][65];
  const int tid = threadIdx.x;
  const int kb = blockIdx.y * 64, nb = blockIdx.x * 64;
  #pragma unroll
  for (int i = 0; i < 4; i++){
    int row = (tid >> 4) + i*16;
    int c4  = (tid & 15) * 4;
    float4 v = *reinterpret_cast<const float4*>(W + (size_t)(kb+row)*N + nb + c4);
    t[row][c4] = v.x; t[row][c4+1] = v.y; t[row][c4+2] = v.z; t[row][c4+3] = v.w;
  }
  __syncthreads();
  int n  = tid >> 2;
  int kc = (tid & 3) * 16;
  u16 tmp[16];
  #pragma unroll
  for (int j = 0; j < 16; j++) tmp[j] = f2us(t[kc+j][n]);
  u16* dst = Wt + (size_t)(noff + nb + n)*ldt + kb + kc;
  *reinterpret_cast<i32x4*>(dst)     = *reinterpret_cast<const i32x4*>(tmp);
  *reinterpret_cast<i32x4*>(dst + 8) = *reinterpret_cast<const i32x4*>(tmp + 8);
}

// ---------------------------------------------- deep-pipelined 256² GEMM (v8)
// (unchanged from round 8 — at the ~900 TF structure plateau)
template<int EPI>
__global__ __launch_bounds__(512, 2)
void gemm8(const u16* __restrict__ A_, int lda,
           const u16* __restrict__ Bt_, int ldb,
           int K, int N, int kspl,
           const float* __restrict__ b0, const float* __restrict__ b1,
           const float* __restrict__ b2, const float* __restrict__ b3,
           u16* __restrict__ qkvo, u16* __restrict__ hcat,
           float* __restrict__ outf)
{
  extern __shared__ __align__(16) u16 lds[];   // 65536 u16 = 128 KiB
  const int tid = threadIdx.x, lane = tid & 63, wid = tid >> 6;
  const int l15 = lane & 15, lhi = lane >> 4;
  const int wm = wid >> 2, wn = wid & 3;
  const int NKH = K / 32;   // K-halves; must be %8==0 and >=16

  const u16* Ag = A_  + (size_t)blockIdx.z * kspl;
  const u16* Bg = Bt_ + (size_t)blockIdx.z * kspl;

  const int nwg = gridDim.x;
  int orig = blockIdx.x;
  int qq = nwg >> 3, rr = nwg & 7;
  int xcd = orig & 7, loc = orig >> 3;
  int wg = (xcd < rr ? xcd*(qq+1) : rr*(qq+1) + (xcd-rr)*qq) + loc;
  const int m0 = (wg % MB) * 256;
  const int n0 = (wg / MB) * 256;

  const u16 *gA0, *gA1, *gB0, *gB1;
  {
    size_t offA[2], offB[2];
    #pragma unroll
    for (int q = 0; q < 2; q++){
      int Lb = q*8192 + tid*16;
      int r  = Lb >> 7;
      int gp = (Lb >> 4) & 7;
      int g  = gp ^ (r & 7);
      int row = 2*r + (g >> 2);
      int ke  = (g & 3) * 8;
      offA[q] = (size_t)(m0 + row)*lda + ke;
      offB[q] = (size_t)(n0 + row)*ldb + ke;
    }
    gA0 = Ag + offA[0]; gA1 = Ag + offA[1];
    gB0 = Bg + offB[0]; gB1 = Bg + offB[1];
  }
  u16* dA0 = lds + tid*8;
  u16* dA1 = lds + 4096 + tid*8;
  u16* dB0 = lds + 32768 + tid*8;
  u16* dB1 = lds + 36864 + tid*8;

  const char *pa0, *pb0;
  {
    const char* LB = (const char*)lds;
    int Ra = wm*128 + l15;
    pa0 = LB + (Ra>>1)*128 + (((((Ra&1)<<2)|lhi) ^ ((Ra>>1)&7))*16);
    int Rb = wn*64 + l15;
    pb0 = LB + 65536 + (Rb>>1)*128 + (((((Rb&1)<<2)|lhi) ^ ((Rb>>1)&7))*16);
  }

  f32x4 acc[8][4];
  #pragma unroll
  for (int i = 0; i < 8; i++)
    #pragma unroll
    for (int j = 0; j < 4; j++){ f32x4 z = {0.f,0.f,0.f,0.f}; acc[i][j] = z; }

  #define LD8(P_) (*reinterpret_cast<const s16x8*>(P_))
  #define MFMA_ALL(AF_, BF_) do{                                               \
    _Pragma("unroll") for (int a_=0;a_<8;a_++)                                 \
      _Pragma("unroll") for (int nf_=0;nf_<4;nf_++)                            \
        acc[a_][nf_] = __builtin_amdgcn_mfma_f32_16x16x32_bf16(                \
            (AF_)[a_], (BF_)[nf_], acc[a_][nf_], 0, 0, 0); }while(0)

  #define PHASEP(RP_,SP_,DOI_,GOFF_,VN_) do{                                   \
    s16x8 af[8], bf[4];                                                        \
    af[0] = LD8(pa0 + (RP_)*16384);                                            \
    _Pragma("unroll") for (int i_=0;i_<4;i_++)                                 \
      bf[i_] = LD8(pb0 + (RP_)*16384 + i_*1024);                               \
    _Pragma("unroll") for (int i_=1;i_<8;i_++)                                 \
      af[i_] = LD8(pa0 + (RP_)*16384 + (i_>>2)*4096 + (i_&3)*1024);            \
    if (DOI_){                                                                 \
      gload16(gA0+(GOFF_), dA0+(SP_)*8192); gload16(gA1+(GOFF_), dA1+(SP_)*8192);\
      gload16(gB0+(GOFF_), dB0+(SP_)*8192); gload16(gB1+(GOFF_), dB1+(SP_)*8192);\
    }                                                                          \
    __builtin_amdgcn_s_setprio(1);                                             \
    MFMA_ALL(af, bf);                                                          \
    __builtin_amdgcn_s_setprio(0);                                             \
    LGKM0();                                                                   \
    VMW(VN_);                                                                  \
    BAR();                                                                     \
  }while(0)

  gload16(gA0,    dA0);        gload16(gA1,    dA1);
  gload16(gB0,    dB0);        gload16(gB1,    dB1);
  gload16(gA0+32, dA0+8192);   gload16(gA1+32, dA1+8192);
  gload16(gB0+32, dB0+8192);   gload16(gB1+32, dB1+8192);
  gload16(gA0+64, dA0+16384);  gload16(gA1+64, dA1+16384);
  gload16(gB0+64, dB0+16384);  gload16(gB1+64, dB1+16384);
  VMW(8);   // region 0 landed
  BAR();

  const int nblk = NKH >> 3;
  for (int b = 0; b < nblk - 1; b++){
    PHASEP(0,3,1, 96,8); PHASEP(1,0,1,128,8); PHASEP(2,1,1,160,8); PHASEP(3,2,1,192,8);
    PHASEP(0,3,1,224,8); PHASEP(1,0,1,256,8); PHASEP(2,1,1,288,8); PHASEP(3,2,1,320,8);
    gA0 += 256; gA1 += 256; gB0 += 256; gB1 += 256;
  }
  PHASEP(0,3,1, 96,8); PHASEP(1,0,1,128,8); PHASEP(2,1,1,160,8); PHASEP(3,2,1,192,8);
  PHASEP(0,3,1,224,8); PHASEP(1,0,0,  0,4); PHASEP(2,1,0,  0,0); PHASEP(3,2,0,  0,0);

  #undef PHASEP
  #undef MFMA_ALL
  #undef LD8

  #pragma unroll
  for (int a = 0; a < 8; a++){
    #pragma unroll
    for (int nf = 0; nf < 4; nf++){
      int col = n0 + wn*64 + nf*16 + l15;
      #pragma unroll
      for (int r = 0; r < 4; r++){
        int row = m0 + wm*128 + a*16 + lhi*4 + r;
        float v = acc[a][nf][r];
        if constexpr (EPI == 0){
          if (col < QKVD){
            const float* bp = b0; int c = col;
            if (c >= 6144){ bp = b2; c -= 6144; }
            else if (c >= 3072){ bp = b1; c -= 3072; }
            qkvo[(size_t)row*QKVD + col] = f2us(v + bp[c]);
          } else {
            int c2 = col - QKVD;
            hcat[(size_t)row*CATD + HIDDEN + c2] = f2us(gelu_tanh(v + b3[c2]));
          }
        } else {
          outf[(size_t)blockIdx.z*NTOK*HIDDEN + (size_t)row*HIDDEN + col] = v;
        }
      }
    }
  }
}

// ------------------------------------- split-K reduce + gate/residual epilogue
__global__ __launch_bounds__(256)
void reduce_out(const float* __restrict__ part, const float* __restrict__ bout,
                const float* __restrict__ emb,
                const float* __restrict__ hs, const float* __restrict__ ehs,
                float* __restrict__ outp)
{
  int row = blockIdx.x;
  const float* res = (row < SIMG) ? hs + (size_t)row*HIDDEN
                                  : ehs + (size_t)(row - SIMG)*HIDDEN;
  #pragma unroll
  for (int i = 0; i < 3; i++){
    int col = i*1024 + threadIdx.x*4;
    float4 a = *reinterpret_cast<const float4*>(part + (size_t)row*HIDDEN + col);
    float4 b = *reinterpret_cast<const float4*>(part + (size_t)NTOK*HIDDEN + (size_t)row*HIDDEN + col);
    float4 rr = *reinterpret_cast<const float4*>(res + col);
    float4 bb = *reinterpret_cast<const float4*>(bout + col);
    float4 gg = *reinterpret_cast<const float4*>(emb + 2*HIDDEN + col);
    float4 o;
    o.x = gg.x*(a.x+b.x+bb.x) + rr.x;
    o.y = gg.y*(a.y+b.y+bb.y) + rr.y;
    o.z = gg.z*(a.z+b.z+bb.z) + rr.z;
    o.w = gg.w*(a.w+b.w+bb.w) + rr.w;
    *reinterpret_cast<float4*>(outp + (size_t)row*HIDDEN + col) = o;
  }
}

// ------------------------------------------- rmsnorm + rope on q,k (in place)
__global__ __launch_bounds__(256)
void qk_post(u16* __restrict__ qkv,
             const float* __restrict__ nqw, const float* __restrict__ nkw,
             const float* __restrict__ fc)
{
  int rid = blockIdx.x*4 + (threadIdx.x >> 6);
  int lane = threadIdx.x & 63;
  int isK = rid >= NTOK*HEADS;
  int r = isK ? rid - NTOK*HEADS : rid;
  int token = r / HEADS, head = r % HEADS;
  u16* p = qkv + (size_t)token*QKVD + (isK ? HIDDEN : 0) + head*HD + lane*2;
  unsigned int u = *reinterpret_cast<unsigned int*>(p);
  float v0 = us2f((u16)(u & 0xffff));
  float v1 = us2f((u16)(u >> 16));
  float ss = v0*v0 + v1*v1;
  #pragma unroll
  for (int d = 1; d < 64; d <<= 1) ss += __shfl_xor(ss, d);
  float rs = rsqrtf(ss * (1.0f/HD) + LN_EPS);
  const float* wv = isK ? nkw : nqw;
  v0 *= rs * wv[lane*2];
  v1 *= rs * wv[lane*2+1];
  if (token < SIMG){
    const float* f = fc + (size_t)token*(2*HD);
    float c0 = f[lane*2],      c1 = f[lane*2+1];
    float s0 = f[HD + lane*2], s1 = f[HD + lane*2+1];
    float o0 = v0*c0 - v1*s0;
    float o1 = v1*c1 + v0*s1;
    v0 = o0; v1 = o1;
  }
  unsigned int uo = (unsigned int)f2us(v0) | ((unsigned int)f2us(v1) << 16);
  *reinterpret_cast<unsigned int*>(p) = uo;
}

// ------------------------------------------------------------ flash attention
// v9: 8-wave blocks, Q=128 rows/block (each wave owns 16 rows). Q fragments
// loaded DIRECTLY global->reg (no Q LDS, read once). K/V staged in LDS shared
// by 8 waves (per-wave staging cost halved vs 4-wave), reg-prefetched one
// tile ahead (T14). LDS 53KB -> 2 blocks/CU -> up to 4 waves/SIMD so one
// wave's softmax overlaps other waves' MFMA.
__global__ __launch_bounds__(512)
void attn_kernel(const u16* __restrict__ qkv, u16* __restrict__ hcat)
{
  __shared__ __align__(16) u16 Ks[64][136];
  __shared__ __align__(16) u16 Vt[128][72];
  __shared__ __align__(16) u16 Ps[128][72];

  const int tid = threadIdx.x, lane = tid & 63, w = tid >> 6;   // w: 0..7
  const int head = blockIdx.y;
  const int l15 = lane & 15, lhi = lane >> 4;
  const int q0 = blockIdx.x * 128;
  const float scale = 0.08838834764831845f;

  // Q fragments direct from global (read once; 16 rows per wave)
  s16x8 qf[4];
  {
    const u16* qrow = qkv + (size_t)(q0 + w*16 + l15)*QKVD + head*HD;
    #pragma unroll
    for (int ks = 0; ks < 4; ks++)
      qf[ks] = *reinterpret_cast<const s16x8*>(qrow + ks*32 + lhi*8);
  }

  // K staging mapping: 2 chunks of 8 elems per thread (64 rows x 16 chunks)
  int krow[2], kd0[2];
  #pragma unroll
  for (int i = 0; i < 2; i++){ int c = tid + 512*i; krow[i] = c >> 4; kd0[i] = (c & 15)*8; }
  // V staging mapping: 4 kv-rows x 4 d per thread
  const int vd0   = (tid & 31) * 4;     // d range [vd0, vd0+4)
  const int vbase = (tid >> 5) * 4;     // kv rows [vbase, vbase+4)
  // transposed write base: Vt[d][col], col = ((kv>>3)^((d>>3)&7))<<3 | (kv&7)
  char* vwp = (char*)(&Vt[0][0]) + vd0*144 + (((vbase>>3) ^ ((vd0>>3)&7))*16) + (vbase&7)*2;

  i32x4 kr0, kr1;
  i32x2 vr0, vr1, vr2, vr3;
  {
    const u16* kbp = qkv + HIDDEN + (size_t)head*HD;
    const u16* vbp = qkv + 2*HIDDEN + (size_t)head*HD;
    kr0 = *reinterpret_cast<const i32x4*>(kbp + (size_t)(krow[0])*QKVD + kd0[0]);
    kr1 = *reinterpret_cast<const i32x4*>(kbp + (size_t)(krow[1])*QKVD + kd0[1]);
    vr0 = *reinterpret_cast<const i32x2*>(vbp + (size_t)(vbase+0)*QKVD + vd0);
    vr1 = *reinterpret_cast<const i32x2*>(vbp + (size_t)(vbase+1)*QKVD + vd0);
    vr2 = *reinterpret_cast<const i32x2*>(vbp + (size_t)(vbase+2)*QKVD + vd0);
    vr3 = *reinterpret_cast<const i32x2*>(vbp + (size_t)(vbase+3)*QKVD + vd0);
  }

  f32x4 O[8];
  #pragma unroll
  for (int i = 0; i < 8; i++){ f32x4 z = {0.f,0.f,0.f,0.f}; O[i] = z; }
  float mrow[4], lrow[4];
  #pragma unroll
  for (int r = 0; r < 4; r++){ mrow[r] = -1e30f; lrow[r] = 0.f; }

  for (int kv0 = 0; kv0 < NTOK; kv0 += 64){
    // write staged K (b128) and V (transposed: pack 4 kv per d, b64 writes)
    *reinterpret_cast<i32x4*>(&Ks[krow[0]][kd0[0]]) = kr0;
    *reinterpret_cast<i32x4*>(&Ks[krow[1]][kd0[1]]) = kr1;
    #pragma unroll
    for (int dd = 0; dd < 4; dd++){
      u32 a0 = (u32)(dd & 1 ? ((u32)vr0[dd>>1]) >> 16 : ((u32)vr0[dd>>1]) & 0xffff);
      u32 a1 = (u32)(dd & 1 ? ((u32)vr1[dd>>1]) >> 16 : ((u32)vr1[dd>>1]) & 0xffff);
      u32 a2 = (u32)(dd & 1 ? ((u32)vr2[dd>>1]) >> 16 : ((u32)vr2[dd>>1]) & 0xffff);
      u32 a3 = (u32)(dd & 1 ? ((u32)vr3[dd>>1]) >> 16 : ((u32)vr3[dd>>1]) & 0xffff);
      u32x2 pk; pk[0] = a0 | (a1 << 16); pk[1] = a2 | (a3 << 16);
      *reinterpret_cast<u32x2*>(vwp + dd*144) = pk;
    }
    __syncthreads();   // tile staged

    // prefetch next tile into regs
    if (kv0 + 64 < NTOK){
      const u16* kbp = qkv + (size_t)(kv0+64)*QKVD + HIDDEN + (size_t)head*HD;
      const u16* vbp = qkv + (size_t)(kv0+64)*QKVD + 2*HIDDEN + (size_t)head*HD;
      kr0 = *reinterpret_cast<const i32x4*>(kbp + (size_t)(krow[0])*QKVD + kd0[0]);
      kr1 = *reinterpret_cast<const i32x4*>(kbp + (size_t)(krow[1])*QKVD + kd0[1]);
      vr0 = *reinterpret_cast<const i32x2*>(vbp + (size_t)(vbase+0)*QKVD + vd0);
      vr1 = *reinterpret_cast<const i32x2*>(vbp + (size_t)(vbase+1)*QKVD + vd0);
      vr2 = *reinterpret_cast<const i32x2*>(vbp + (size_t)(vbase+2)*QKVD + vd0);
      vr3 = *reinterpret_cast<const i32x2*>(vbp + (size_t)(vbase+3)*QKVD + vd0);
    }

    // S = Q K^T (wave's 16 rows x 64 kv)
    f32x4 S[4];
    #pragma unroll
    for (int nf = 0; nf < 4; nf++){ f32x4 z = {0.f,0.f,0.f,0.f}; S[nf] = z; }
    #pragma unroll
    for (int ks = 0; ks < 4; ks++){
      #pragma unroll
      for (int nf = 0; nf < 4; nf++){
        s16x8 b = *reinterpret_cast<const s16x8*>(&Ks[nf*16 + l15][ks*32 + lhi*8]);
        S[nf] = __builtin_amdgcn_mfma_f32_16x16x32_bf16(qf[ks], b, S[nf], 0, 0, 0);
      }
    }
    #pragma unroll
    for (int nf = 0; nf < 4; nf++)
      #pragma unroll
      for (int r = 0; r < 4; r++) S[nf][r] *= scale;

    // online softmax (row = w*16 + lhi*4 + r)
    float fsc[4];
    #pragma unroll
    for (int r = 0; r < 4; r++){
      float mx = -1e30f;
      #pragma unroll
      for (int nf = 0; nf < 4; nf++) mx = fmaxf(mx, S[nf][r]);
      #pragma unroll
      for (int d = 1; d < 16; d <<= 1) mx = fmaxf(mx, __shfl_xor(mx, d));
      float mn = fmaxf(mrow[r], mx);
      float f = __expf(mrow[r] - mn);
      mrow[r] = mn; fsc[r] = f;
      float lsum = 0.f;
      int prow = w*16 + lhi*4 + r;
      #pragma unroll
      for (int nf = 0; nf < 4; nf++){
        float pvl = __expf(S[nf][r] - mn);
        lsum += pvl;
        int pcol = nf*16 + l15;
        int col = (((pcol>>3) ^ (prow&7)) << 3) | (pcol & 7);
        Ps[prow][col] = f2us(pvl);
      }
      #pragma unroll
      for (int d = 1; d < 16; d <<= 1) lsum += __shfl_xor(lsum, d);
      lrow[r] = lrow[r]*f + lsum;
    }
    #pragma unroll
    for (int nf = 0; nf < 8; nf++)
      #pragma unroll
      for (int r = 0; r < 4; r++) O[nf][r] *= fsc[r];

    // O += P V  (Ps rows are wave-private; same-wave RAW via lgkm)
    #pragma unroll
    for (int ks = 0; ks < 2; ks++){
      int prow = w*16 + l15;
      int cb = ((ks*4 + lhi) ^ (prow & 7)) << 3;
      s16x8 a = *reinterpret_cast<const s16x8*>(&Ps[prow][cb]);
      #pragma unroll
      for (int nf = 0; nf < 8; nf++){
        int d = nf*16 + l15;
        int vb = ((ks*4 + lhi) ^ ((d>>3)&7)) << 3;
        s16x8 b = *reinterpret_cast<const s16x8*>(&Vt[d][vb]);
        O[nf] = __builtin_amdgcn_mfma_f32_16x16x32_bf16(a, b, O[nf], 0, 0, 0);
      }
    }
    __syncthreads();   // all Ks/Vt reads done before next tile's writes
  }

  #pragma unroll
  for (int nf = 0; nf < 8; nf++){
    #pragma unroll
    for (int r = 0; r < 4; r++){
      int row = q0 + w*16 + lhi*4 + r;
      int col = head*HD + nf*16 + l15;
      hcat[(size_t)row*CATD + col] = f2us(O[nf][r] / lrow[r]);
    }
  }
}

// ---------------------------------------------------------------------- host
extern "C" void kernel_launch(void* const* d_in, const int* in_sizes, int n_in,
                              void* d_out, int out_size, void* d_ws, size_t ws_size,
                              hipStream_t stream)
{
  const float* hs    = (const float*)d_in[0];
  const float* ehs   = (const float*)d_in[1];
  const float* temb  = (const float*)d_in[2];
  const float* fc    = (const float*)d_in[3];
  const float* wnorm = (const float*)d_in[4];
  const float* bnorm = (const float*)d_in[5];
  const float* wq    = (const float*)d_in[6];
  const float* bq    = (const float*)d_in[7];
  const float* wk    = (const float*)d_in[8];
  const float* bk    = (const float*)d_in[9];
  const float* wv    = (const float*)d_in[10];
  const float* bv    = (const float*)d_in[11];
  const float* nqw   = (const float*)d_in[12];
  const float* nkw   = (const float*)d_in[13];
  const float* wmlp  = (const float*)d_in[14];
  const float* bmlp  = (const float*)d_in[15];
  const float* wout  = (const float*)d_in[16];
  const float* bout  = (const float*)d_in[17];
  float* outp = (float*)d_out;

  char* ws = (char*)d_ws;
  float* emb  = (float*)ws;                               // 36864 B
  float* part = (float*)(ws + 36864);                     // 294912 B
  u16* nx     = (u16*)(ws + 36864 + 294912);
  u16* qkv    = nx  + (size_t)NTOK*HIDDEN;
  u16* hcat   = qkv + (size_t)NTOK*QKVD;
  u16* Wt     = hcat + (size_t)NTOK*CATD;
  float* partial = (float*)nx;  // aliases nx+qkv (dead by out-proj time)

  hipFuncSetAttribute((const void*)gemm8<0>, hipFuncAttributeMaxDynamicSharedMemorySize, 131072);
  hipFuncSetAttribute((const void*)gemm8<1>, hipFuncAttributeMaxDynamicSharedMemorySize, 131072);

  emb_partial<<<dim3(36,8), 256, 0, stream>>>(temb, wnorm, part);
  emb_reduce<<<36, 256, 0, stream>>>(part, bnorm, emb);
  ln_mod<<<NTOK, 256, 0, stream>>>(hs, ehs, emb, nx);

  transpose_w<<<dim3(48,48), 256, 0, stream>>>(wq,   Wt, HIDDEN, HIDDEN, HIDDEN, 0);
  transpose_w<<<dim3(48,48), 256, 0, stream>>>(wk,   Wt, HIDDEN, HIDDEN, HIDDEN, HIDDEN);
  transpose_w<<<dim3(48,48), 256, 0, stream>>>(wv,   Wt, HIDDEN, HIDDEN, HIDDEN, 2*HIDDEN);
  transpose_w<<<dim3(192,48), 256, 0, stream>>>(wmlp, Wt, HIDDEN, MLPD, HIDDEN, QKVD);

  // fused QKV+MLP GEMM: [2304 x 21504], K=3072 (NKH=96)
  gemm8<0><<<dim3((FUSEN/256)*MB, 1, 1), 512, 131072, stream>>>(
      nx, HIDDEN, Wt, HIDDEN, HIDDEN, FUSEN, 0,
      bq, bk, bv, bmlp, qkv, hcat, nullptr);

  transpose_w<<<dim3(48,240), 256, 0, stream>>>(wout, Wt, CATD, HIDDEN, CATD, 0);

  qk_post<<<(2*NTOK*HEADS)/4, 256, 0, stream>>>(qkv, nqw, nkw, fc);
  attn_kernel<<<dim3(NTOK/128, HEADS), 512, 0, stream>>>(qkv, hcat);

  // out-proj: split-K=2 (NKH=240 each), f32 partials
  gemm8<1><<<dim3((HIDDEN/256)*MB, 1, 2), 512, 131072, stream>>>(
      hcat, CATD, Wt, CATD, CATD/2, HIDDEN, CATD/2,
      nullptr, nullptr, nullptr, nullptr, nullptr, nullptr, partial);

  reduce_out<<<NTOK, 256, 0, stream>>>(partial, bout, emb, hs, ehs, outp);
}

// Round 10
// 951.934 us; speedup vs baseline: 1.0174x; 1.0003x over previous
//
#include <hip/hip_runtime.h>
#include <hip/hip_bf16.h>

typedef unsigned short u16;
typedef short s16x8 __attribute__((ext_vector_type(8)));
typedef float f32x4 __attribute__((ext_vector_type(4)));
typedef int   i32x4 __attribute__((ext_vector_type(4)));
typedef int   i32x2 __attribute__((ext_vector_type(2)));
typedef u16   u16x4 __attribute__((ext_vector_type(4)));
typedef unsigned int u32;
typedef u32   u32x2 __attribute__((ext_vector_type(2)));

#define HEADS  24
#define HD     128
#define HIDDEN 3072
#define MLPD   12288
#define NTOK   2304
#define SIMG   2048
#define NEMB   9216
#define CATD   15360   // HIDDEN + MLPD
#define QKVD   9216    // 3*HIDDEN
#define FUSEN  21504   // QKVD + MLPD
#define LN_EPS 1e-6f
#define MB     9       // 2304/256 M-blocks

__device__ __forceinline__ u16 f2us(float f){
  __hip_bfloat16 h = __float2bfloat16(f);
  return *reinterpret_cast<u16*>(&h);
}
__device__ __forceinline__ float us2f(u16 u){
  __hip_bfloat16 h;
  *reinterpret_cast<u16*>(&h) = u;
  return __bfloat162float(h);
}
__device__ __forceinline__ float gelu_tanh(float x){
  float y = 0.7978845608028654f*(x + 0.044715f*x*x*x);
  y = fminf(fmaxf(y, -12.f), 12.f);
  float e = __expf(-2.f*y);
  float t = (1.f - e) / (1.f + e);
  return 0.5f*x*(1.0f + t);
}
__device__ __forceinline__ void gload16(const u16* g, u16* l){
  __builtin_amdgcn_global_load_lds(
      (const __attribute__((address_space(1))) void*)g,
      (__attribute__((address_space(3))) void*)l, 16, 0, 0);
}
#define BAR() do{ asm volatile("":::"memory"); __builtin_amdgcn_s_barrier(); asm volatile("":::"memory"); }while(0)
#define LGKM0() asm volatile("s_waitcnt lgkmcnt(0)":::"memory")
#define VMW_(n) asm volatile("s_waitcnt vmcnt(" #n ")":::"memory")
#define VMW(n) VMW_(n)

// ---------------------------------------------------------------- emb kernels
__global__ __launch_bounds__(256)
void emb_partial(const float* __restrict__ temb, const float* __restrict__ wn,
                 float* __restrict__ partial)
{
  __shared__ float ls[384];
  int tid = threadIdx.x;
  int kb = blockIdx.y * 384;
  for (int i = tid; i < 384; i += 256){
    float t = temb[kb + i];
    ls[i] = t / (1.0f + __expf(-t));
  }
  __syncthreads();
  int j = blockIdx.x*256 + tid;
  const float* wp = wn + (size_t)kb*NEMB + j;
  float acc = 0.f;
  #pragma unroll 8
  for (int i = 0; i < 384; i++){ acc = fmaf(ls[i], wp[0], acc); wp += NEMB; }
  partial[blockIdx.y*NEMB + j] = acc;
}

__global__ __launch_bounds__(256)
void emb_reduce(const float* __restrict__ partial, const float* __restrict__ bn,
                float* __restrict__ emb)
{
  int j = blockIdx.x*256 + threadIdx.x;
  float s = bn[j];
  #pragma unroll
  for (int r = 0; r < 8; r++) s += partial[r*NEMB + j];
  emb[j] = s;
}

// ------------------------------------------------- layernorm + modulate (bf16)
__global__ __launch_bounds__(256)
void ln_mod(const float* __restrict__ hs, const float* __restrict__ ehs,
            const float* __restrict__ emb, u16* __restrict__ nx)
{
  int row = blockIdx.x;
  const float* x = (row < SIMG) ? hs + (size_t)row*HIDDEN
                                : ehs + (size_t)(row - SIMG)*HIDDEN;
  int tid = threadIdx.x;
  float vals[12];
  float s = 0.f, ss = 0.f;
  #pragma unroll
  for (int i = 0; i < 3; i++){
    float4 v = *reinterpret_cast<const float4*>(x + i*1024 + tid*4);
    vals[i*4+0]=v.x; vals[i*4+1]=v.y; vals[i*4+2]=v.z; vals[i*4+3]=v.w;
    s += v.x+v.y+v.z+v.w;
    ss += v.x*v.x + v.y*v.y + v.z*v.z + v.w*v.w;
  }
  #pragma unroll
  for (int d = 1; d < 64; d <<= 1){ s += __shfl_xor(s, d); ss += __shfl_xor(ss, d); }
  __shared__ float red[8];
  if ((tid & 63) == 0){ red[tid>>6] = s; red[4 + (tid>>6)] = ss; }
  __syncthreads();
  s  = red[0]+red[1]+red[2]+red[3];
  ss = red[4]+red[5]+red[6]+red[7];
  float mu = s * (1.0f/HIDDEN);
  float var = ss * (1.0f/HIDDEN) - mu*mu;
  float rs = rsqrtf(var + LN_EPS);
  #pragma unroll
  for (int i = 0; i < 3; i++){
    int col = i*1024 + tid*4;
    u16x4 o;
    #pragma unroll
    for (int j = 0; j < 4; j++){
      float nv = (vals[i*4+j] - mu) * rs;
      float outv = nv * (1.0f + emb[HIDDEN + col + j]) + emb[col + j];
      o[j] = f2us(outv);
    }
    *reinterpret_cast<u16x4*>(nx + (size_t)row*HIDDEN + col) = o;
  }
}

// ------------------------------------------- W[K][N] f32 -> Wt[noff+n][k] bf16
__global__ __launch_bounds__(256)
void transpose_w(const float* __restrict__ W, u16* __restrict__ Wt,
                 int K, int N, int ldt, int noff)
{
  __shared__ float t[64][65];
  const int tid = threadIdx.x;
  const int kb = blockIdx.y * 64, nb = blockIdx.x * 64;
  #pragma unroll
  for (int i = 0; i < 4; i++){
    int row = (tid >> 4) + i*16;
    int c4  = (tid & 15) * 4;
    float4 v = *reinterpret_cast<const float4*>(W + (size_t)(kb+row)*N + nb + c4);
    t[row][c4] = v.x; t[row][c4+1] = v.y; t[row][c4+2] = v.z; t[row][c4+3] = v.w;
  }
  __syncthreads();
  int n  = tid >> 2;
  int kc = (tid & 3) * 16;
  u16 tmp[16];
  #pragma unroll
  for (int j = 0; j < 16; j++) tmp[j] = f2us(t[kc+j][n]);
  u16* dst = Wt + (size_t)(noff + nb + n)*ldt + kb + kc;
  *reinterpret_cast<i32x4*>(dst)     = *reinterpret_cast<const i32x4*>(tmp);
  *reinterpret_cast<i32x4*>(dst + 8) = *reinterpret_cast<const i32x4*>(tmp + 8);
}

// ------------------------------------------ m201-faithful 8-phase 256² GEMM
// 4 phases per K-tile, quadrant order (m0n0)(m0n1)(m1n1)(m1n0); each phase:
// {ds-read quadrant frags, stage <=1 region (2 gload_lds), BAR, lgkm0,
// setprio(1), 16 MFMA, setprio(0), BAR}. vmcnt(2) ONCE per tile at ph4 —
// counted, never drained in the main loop. Stage ledger: ph1 A(t+1,k1)+
// B(t+1,k0); ph2 B(t+1,k1); ph4 A(t+2,k0). Every staged region's last
// reader finished >=1 barrier earlier (A own-buf last read ph3 < ph4 stage;
// other-buf regions last read in prev tile). Single frag set (48 VGPR).
template<int EPI>
__global__ __launch_bounds__(512, 2)
void gemm8(const u16* __restrict__ A_, int lda,
           const u16* __restrict__ Bt_, int ldb,
           int K, int N, int kspl,
           const float* __restrict__ b0, const float* __restrict__ b1,
           const float* __restrict__ b2, const float* __restrict__ b3,
           u16* __restrict__ qkvo, u16* __restrict__ hcat,
           float* __restrict__ outf)
{
  extern __shared__ __align__(16) u16 lds[];   // 65536 u16 = 128 KiB
  const int tid = threadIdx.x, lane = tid & 63, wid = tid >> 6;
  const int l15 = lane & 15, lhi = lane >> 4;
  const int wm = wid >> 2, wn = wid & 3;
  const int NT = K / 64;    // K-tiles; must be even and >= 4

  const u16* Ag = A_  + (size_t)blockIdx.z * kspl;
  const u16* Bg = Bt_ + (size_t)blockIdx.z * kspl;

  // bijective XCD-aware swizzle (m204), column-major block order
  const int nwg = gridDim.x;
  int orig = blockIdx.x;
  int qq = nwg >> 3, rr = nwg & 7;
  int xcd = orig & 7, loc = orig >> 3;
  int wg = (xcd < rr ? xcd*(qq+1) : rr*(qq+1) + (xcd-rr)*qq) + loc;
  const int m0 = (wg % MB) * 256;
  const int n0 = (wg / MB) * 256;

  // staging global pointers (2 issues per 16KB region per wave: halves 0/1)
  const u16 *gA0, *gA1, *gB0, *gB1;
  {
    size_t offA[2], offB[2];
    #pragma unroll
    for (int q = 0; q < 2; q++){
      int Lb = q*8192 + tid*16;          // byte offset within region
      int r  = Lb >> 7;                  // LDS row (128B rows)
      int gp = (Lb >> 4) & 7;
      int g  = gp ^ (r & 7);
      int row = 2*r + (g >> 2);
      int ke  = (g & 3) * 8;
      offA[q] = (size_t)(m0 + row)*lda + ke;
      offB[q] = (size_t)(n0 + row)*ldb + ke;
    }
    gA0 = Ag + offA[0]; gA1 = Ag + offA[1];
    gB0 = Bg + offB[0]; gB1 = Bg + offB[1];
  }

  // per-lane LDS read bases; all deltas are compile-time immediates:
  // A frag (p,kh,qm,mf): pa0 + (p*2+kh)*16384 + qm*4096 + mf*1024
  // B frag (p,kh,qn,nf): pb0 + (p*2+kh)*16384 + qn*2048 + nf*1024
  const char *pa0, *pb0;
  {
    const char* LB = (const char*)lds;
    int Ra = wm*128 + l15;
    pa0 = LB + (Ra>>1)*128 + (((((Ra&1)<<2)|lhi) ^ ((Ra>>1)&7))*16);
    int Rb = wn*64 + l15;
    pb0 = LB + 65536 + (Rb>>1)*128 + (((((Rb&1)<<2)|lhi) ^ ((Rb>>1)&7))*16);
  }

  f32x4 acc[8][4];
  #pragma unroll
  for (int i = 0; i < 8; i++)
    #pragma unroll
    for (int j = 0; j < 4; j++){ f32x4 z = {0.f,0.f,0.f,0.f}; acc[i][j] = z; }

  s16x8 aset[8], bset[4];

  #define LD8(P_) (*reinterpret_cast<const s16x8*>(P_))
  #define READ_A(QM_, PP_) do{                                                 \
    _Pragma("unroll") for (int kh_=0;kh_<2;kh_++)                              \
      _Pragma("unroll") for (int mf_=0;mf_<4;mf_++)                            \
        aset[kh_*4+mf_] = LD8(pa0 + ((PP_)*2+kh_)*16384 + (QM_)*4096 + mf_*1024);}while(0)
  #define READ_B(QN_, PP_) do{                                                 \
    _Pragma("unroll") for (int kh_=0;kh_<2;kh_++)                              \
      _Pragma("unroll") for (int nf_=0;nf_<2;nf_++)                            \
        bset[kh_*2+nf_] = LD8(pb0 + ((PP_)*2+kh_)*16384 + (QN_)*2048 + nf_*1024);}while(0)
  #define MM16(QM_, QN_) do{                                                   \
    _Pragma("unroll") for (int kh_=0;kh_<2;kh_++)                              \
      _Pragma("unroll") for (int mf_=0;mf_<4;mf_++)                            \
        _Pragma("unroll") for (int nf_=0;nf_<2;nf_++)                          \
          acc[(QM_)*4+mf_][(QN_)*2+nf_] = __builtin_amdgcn_mfma_f32_16x16x32_bf16(\
              aset[kh_*4+mf_], bset[kh_*2+nf_], acc[(QM_)*4+mf_][(QN_)*2+nf_],0,0,0);}while(0)
  #define STGA(GOFF_, RB_) do{ gload16(gA0+(GOFF_), lds+(RB_)+tid*8);          \
                               gload16(gA1+(GOFF_), lds+(RB_)+4096+tid*8); }while(0)
  #define STGB(GOFF_, RB_) do{ gload16(gB0+(GOFF_), lds+(RB_)+tid*8);          \
                               gload16(gB1+(GOFF_), lds+(RB_)+4096+tid*8); }while(0)
  #define PRIO1() __builtin_amdgcn_s_setprio(1)
  #define PRIO0() __builtin_amdgcn_s_setprio(0)

  // region elem bases: A(p,kh) = (p*2+kh)*8192 ; B(p,kh) = 32768 + (p*2+kh)*8192
  // TILE_FULL(P): stages ph1 A(t+1,k1)+B(t+1,k0), ph2 B(t+1,k1), ph4 A(t+2,k0)
  #define TILE_FULL(P_) do{                                                    \
    /* ph1 (m0,n0) */                                                          \
    READ_A(0,P_); READ_B(0,P_);                                                \
    STGA((P_)?160:96, (P_)?8192:24576);                                        \
    STGB((P_)?128:64, (P_)?32768:49152);                                       \
    BAR(); LGKM0(); PRIO1(); MM16(0,0); PRIO0(); BAR();                        \
    /* ph2 (m0,n1) */                                                          \
    READ_B(1,P_);                                                              \
    STGB((P_)?160:96, (P_)?40960:57344);                                       \
    BAR(); LGKM0(); PRIO1(); MM16(0,1); PRIO0(); BAR();                        \
    /* ph3 (m1,n1) */                                                          \
    READ_A(1,P_);                                                              \
    BAR(); LGKM0(); PRIO1(); MM16(1,1); PRIO0(); BAR();                        \
    /* ph4 (m1,n0) */                                                          \
    READ_B(0,P_);                                                              \
    STGA((P_)?192:128, (P_)?16384:0);                                          \
    BAR(); LGKM0(); PRIO1(); MM16(1,0); PRIO0(); VMW(2); BAR();                \
  }while(0)

  // prologue: A(0,k0) A(0,k1) B(0,k0) B(0,k1) A(1,k0)  (10 loads)
  STGA(0, 0);
  STGA(32, 8192);
  STGB(0, 32768);
  STGB(32, 40960);
  STGA(64, 16384);
  VMW(2);            // tile 0's four regions landed
  BAR();

  const int npair = (NT - 2) >> 1;
  for (int pr = 0; pr < npair; pr++){
    TILE_FULL(0);
    TILE_FULL(1);
    gA0 += 128; gA1 += 128; gB0 += 128; gB1 += 128;
  }
  // tail tile NT-2 (parity 0): stage only tile NT-1's remaining regions
  {
    READ_A(0,0); READ_B(0,0);
    STGA(96, 24576);           // A(NT-1,k1)
    STGB(64, 49152);           // B(NT-1,k0)
    BAR(); LGKM0(); PRIO1(); MM16(0,0); PRIO0(); BAR();
    READ_B(1,0);
    STGB(96, 57344);           // B(NT-1,k1)
    BAR(); LGKM0(); PRIO1(); MM16(0,1); PRIO0(); BAR();
    READ_A(1,0);
    BAR(); LGKM0(); PRIO1(); MM16(1,1); PRIO0(); BAR();
    READ_B(0,0);
    BAR(); LGKM0(); PRIO1(); MM16(1,0); PRIO0(); VMW(0); BAR();
  }
  // tail tile NT-1 (parity 1): no stages, no vmcnt
  {
    READ_A(0,1); READ_B(0,1);
    BAR(); LGKM0(); PRIO1(); MM16(0,0); PRIO0(); BAR();
    READ_B(1,1);
    BAR(); LGKM0(); PRIO1(); MM16(0,1); PRIO0(); BAR();
    READ_A(1,1);
    BAR(); LGKM0(); PRIO1(); MM16(1,1); PRIO0(); BAR();
    READ_B(0,1);
    LGKM0(); PRIO1(); MM16(1,0); PRIO0();
  }

  #undef TILE_FULL
  #undef STGA
  #undef STGB
  #undef MM16
  #undef READ_A
  #undef READ_B
  #undef LD8
  #undef PRIO1
  #undef PRIO0

  // epilogue
  #pragma unroll
  for (int a = 0; a < 8; a++){
    #pragma unroll
    for (int nf = 0; nf < 4; nf++){
      int col = n0 + wn*64 + nf*16 + l15;
      #pragma unroll
      for (int r = 0; r < 4; r++){
        int row = m0 + wm*128 + a*16 + lhi*4 + r;
        float v = acc[a][nf][r];
        if constexpr (EPI == 0){
          if (col < QKVD){
            const float* bp = b0; int c = col;
            if (c >= 6144){ bp = b2; c -= 6144; }
            else if (c >= 3072){ bp = b1; c -= 3072; }
            qkvo[(size_t)row*QKVD + col] = f2us(v + bp[c]);
          } else {
            int c2 = col - QKVD;
            hcat[(size_t)row*CATD + HIDDEN + c2] = f2us(gelu_tanh(v + b3[c2]));
          }
        } else {
          outf[(size_t)blockIdx.z*NTOK*HIDDEN + (size_t)row*HIDDEN + col] = v;
        }
      }
    }
  }
}

// ------------------------------------- split-K reduce + gate/residual epilogue
__global__ __launch_bounds__(256)
void reduce_out(const float* __restrict__ part, const float* __restrict__ bout,
                const float* __restrict__ emb,
                const float* __restrict__ hs, const float* __restrict__ ehs,
                float* __restrict__ outp)
{
  int row = blockIdx.x;
  const float* res = (row < SIMG) ? hs + (size_t)row*HIDDEN
                                  : ehs + (size_t)(row - SIMG)*HIDDEN;
  #pragma unroll
  for (int i = 0; i < 3; i++){
    int col = i*1024 + threadIdx.x*4;
    float4 a = *reinterpret_cast<const float4*>(part + (size_t)row*HIDDEN + col);
    float4 b = *reinterpret_cast<const float4*>(part + (size_t)NTOK*HIDDEN + (size_t)row*HIDDEN + col);
    float4 rr = *reinterpret_cast<const float4*>(res + col);
    float4 bb = *reinterpret_cast<const float4*>(bout + col);
    float4 gg = *reinterpret_cast<const float4*>(emb + 2*HIDDEN + col);
    float4 o;
    o.x = gg.x*(a.x+b.x+bb.x) + rr.x;
    o.y = gg.y*(a.y+b.y+bb.y) + rr.y;
    o.z = gg.z*(a.z+b.z+bb.z) + rr.z;
    o.w = gg.w*(a.w+b.w+bb.w) + rr.w;
    *reinterpret_cast<float4*>(outp + (size_t)row*HIDDEN + col) = o;
  }
}

// ------------------------------------------- rmsnorm + rope on q,k (in place)
__global__ __launch_bounds__(256)
void qk_post(u16* __restrict__ qkv,
             const float* __restrict__ nqw, const float* __restrict__ nkw,
             const float* __restrict__ fc)
{
  int rid = blockIdx.x*4 + (threadIdx.x >> 6);
  int lane = threadIdx.x & 63;
  int isK = rid >= NTOK*HEADS;
  int r = isK ? rid - NTOK*HEADS : rid;
  int token = r / HEADS, head = r % HEADS;
  u16* p = qkv + (size_t)token*QKVD + (isK ? HIDDEN : 0) + head*HD + lane*2;
  unsigned int u = *reinterpret_cast<unsigned int*>(p);
  float v0 = us2f((u16)(u & 0xffff));
  float v1 = us2f((u16)(u >> 16));
  float ss = v0*v0 + v1*v1;
  #pragma unroll
  for (int d = 1; d < 64; d <<= 1) ss += __shfl_xor(ss, d);
  float rs = rsqrtf(ss * (1.0f/HD) + LN_EPS);
  const float* wv = isK ? nkw : nqw;
  v0 *= rs * wv[lane*2];
  v1 *= rs * wv[lane*2+1];
  if (token < SIMG){
    const float* f = fc + (size_t)token*(2*HD);
    float c0 = f[lane*2],      c1 = f[lane*2+1];
    float s0 = f[HD + lane*2], s1 = f[HD + lane*2+1];
    float o0 = v0*c0 - v1*s0;
    float o1 = v1*c1 + v0*s1;
    v0 = o0; v1 = o1;
  }
  unsigned int uo = (unsigned int)f2us(v0) | ((unsigned int)f2us(v1) << 16);
  *reinterpret_cast<unsigned int*>(p) = uo;
}

// ------------------------------------------------------------ flash attention
// v9 (kept): 8-wave blocks, Q=128 rows/block, Q direct global->reg, K/V
// reg-prefetched one tile ahead (T14), packed-b64 transposed V writes.
__global__ __launch_bounds__(512)
void attn_kernel(const u16* __restrict__ qkv, u16* __restrict__ hcat)
{
  __shared__ __align__(16) u16 Ks[64][136];
  __shared__ __align__(16) u16 Vt[128][72];
  __shared__ __align__(16) u16 Ps[128][72];

  const int tid = threadIdx.x, lane = tid & 63, w = tid >> 6;   // w: 0..7
  const int head = blockIdx.y;
  const int l15 = lane & 15, lhi = lane >> 4;
  const int q0 = blockIdx.x * 128;
  const float scale = 0.08838834764831845f;

  s16x8 qf[4];
  {
    const u16* qrow = qkv + (size_t)(q0 + w*16 + l15)*QKVD + head*HD;
    #pragma unroll
    for (int ks = 0; ks < 4; ks++)
      qf[ks] = *reinterpret_cast<const s16x8*>(qrow + ks*32 + lhi*8);
  }

  int krow[2], kd0[2];
  #pragma unroll
  for (int i = 0; i < 2; i++){ int c = tid + 512*i; krow[i] = c >> 4; kd0[i] = (c & 15)*8; }
  const int vd0   = (tid & 31) * 4;
  const int vbase = (tid >> 5) * 4;
  char* vwp = (char*)(&Vt[0][0]) + vd0*144 + (((vbase>>3) ^ ((vd0>>3)&7))*16) + (vbase&7)*2;

  i32x4 kr0, kr1;
  i32x2 vr0, vr1, vr2, vr3;
  {
    const u16* kbp = qkv + HIDDEN + (size_t)head*HD;
    const u16* vbp = qkv + 2*HIDDEN + (size_t)head*HD;
    kr0 = *reinterpret_cast<const i32x4*>(kbp + (size_t)(krow[0])*QKVD + kd0[0]);
    kr1 = *reinterpret_cast<const i32x4*>(kbp + (size_t)(krow[1])*QKVD + kd0[1]);
    vr0 = *reinterpret_cast<const i32x2*>(vbp + (size_t)(vbase+0)*QKVD + vd0);
    vr1 = *reinterpret_cast<const i32x2*>(vbp + (size_t)(vbase+1)*QKVD + vd0);
    vr2 = *reinterpret_cast<const i32x2*>(vbp + (size_t)(vbase+2)*QKVD + vd0);
    vr3 = *reinterpret_cast<const i32x2*>(vbp + (size_t)(vbase+3)*QKVD + vd0);
  }

  f32x4 O[8];
  #pragma unroll
  for (int i = 0; i < 8; i++){ f32x4 z = {0.f,0.f,0.f,0.f}; O[i] = z; }
  float mrow[4], lrow[4];
  #pragma unroll
  for (int r = 0; r < 4; r++){ mrow[r] = -1e30f; lrow[r] = 0.f; }

  for (int kv0 = 0; kv0 < NTOK; kv0 += 64){
    *reinterpret_cast<i32x4*>(&Ks[krow[0]][kd0[0]]) = kr0;
    *reinterpret_cast<i32x4*>(&Ks[krow[1]][kd0[1]]) = kr1;
    #pragma unroll
    for (int dd = 0; dd < 4; dd++){
      u32 a0 = (u32)(dd & 1 ? ((u32)vr0[dd>>1]) >> 16 : ((u32)vr0[dd>>1]) & 0xffff);
      u32 a1 = (u32)(dd & 1 ? ((u32)vr1[dd>>1]) >> 16 : ((u32)vr1[dd>>1]) & 0xffff);
      u32 a2 = (u32)(dd & 1 ? ((u32)vr2[dd>>1]) >> 16 : ((u32)vr2[dd>>1]) & 0xffff);
      u32 a3 = (u32)(dd & 1 ? ((u32)vr3[dd>>1]) >> 16 : ((u32)vr3[dd>>1]) & 0xffff);
      u32x2 pk; pk[0] = a0 | (a1 << 16); pk[1] = a2 | (a3 << 16);
      *reinterpret_cast<u32x2*>(vwp + dd*144) = pk;
    }
    __syncthreads();

    if (kv0 + 64 < NTOK){
      const u16* kbp = qkv + (size_t)(kv0+64)*QKVD + HIDDEN + (size_t)head*HD;
      const u16* vbp = qkv + (size_t)(kv0+64)*QKVD + 2*HIDDEN + (size_t)head*HD;
      kr0 = *reinterpret_cast<const i32x4*>(kbp + (size_t)(krow[0])*QKVD + kd0[0]);
      kr1 = *reinterpret_cast<const i32x4*>(kbp + (size_t)(krow[1])*QKVD + kd0[1]);
      vr0 = *reinterpret_cast<const i32x2*>(vbp + (size_t)(vbase+0)*QKVD + vd0);
      vr1 = *reinterpret_cast<const i32x2*>(vbp + (size_t)(vbase+1)*QKVD + vd0);
      vr2 = *reinterpret_cast<const i32x2*>(vbp + (size_t)(vbase+2)*QKVD + vd0);
      vr3 = *reinterpret_cast<const i32x2*>(vbp + (size_t)(vbase+3)*QKVD + vd0);
    }

    f32x4 S[4];
    #pragma unroll
    for (int nf = 0; nf < 4; nf++){ f32x4 z = {0.f,0.f,0.f,0.f}; S[nf] = z; }
    #pragma unroll
    for (int ks = 0; ks < 4; ks++){
      #pragma unroll
      for (int nf = 0; nf < 4; nf++){
        s16x8 b = *reinterpret_cast<const s16x8*>(&Ks[nf*16 + l15][ks*32 + lhi*8]);
        S[nf] = __builtin_amdgcn_mfma_f32_16x16x32_bf16(qf[ks], b, S[nf], 0, 0, 0);
      }
    }
    #pragma unroll
    for (int nf = 0; nf < 4; nf++)
      #pragma unroll
      for (int r = 0; r < 4; r++) S[nf][r] *= scale;

    float fsc[4];
    #pragma unroll
    for (int r = 0; r < 4; r++){
      float mx = -1e30f;
      #pragma unroll
      for (int nf = 0; nf < 4; nf++) mx = fmaxf(mx, S[nf][r]);
      #pragma unroll
      for (int d = 1; d < 16; d <<= 1) mx = fmaxf(mx, __shfl_xor(mx, d));
      float mn = fmaxf(mrow[r], mx);
      float f = __expf(mrow[r] - mn);
      mrow[r] = mn; fsc[r] = f;
      float lsum = 0.f;
      int prow = w*16 + lhi*4 + r;
      #pragma unroll
      for (int nf = 0; nf < 4; nf++){
        float pvl = __expf(S[nf][r] - mn);
        lsum += pvl;
        int pcol = nf*16 + l15;
        int col = (((pcol>>3) ^ (prow&7)) << 3) | (pcol & 7);
        Ps[prow][col] = f2us(pvl);
      }
      #pragma unroll
      for (int d = 1; d < 16; d <<= 1) lsum += __shfl_xor(lsum, d);
      lrow[r] = lrow[r]*f + lsum;
    }
    #pragma unroll
    for (int nf = 0; nf < 8; nf++)
      #pragma unroll
      for (int r = 0; r < 4; r++) O[nf][r] *= fsc[r];

    #pragma unroll
    for (int ks = 0; ks < 2; ks++){
      int prow = w*16 + l15;
      int cb = ((ks*4 + lhi) ^ (prow & 7)) << 3;
      s16x8 a = *reinterpret_cast<const s16x8*>(&Ps[prow][cb]);
      #pragma unroll
      for (int nf = 0; nf < 8; nf++){
        int d = nf*16 + l15;
        int vb = ((ks*4 + lhi) ^ ((d>>3)&7)) << 3;
        s16x8 b = *reinterpret_cast<const s16x8*>(&Vt[d][vb]);
        O[nf] = __builtin_amdgcn_mfma_f32_16x16x32_bf16(a, b, O[nf], 0, 0, 0);
      }
    }
    __syncthreads();
  }

  #pragma unroll
  for (int nf = 0; nf < 8; nf++){
    #pragma unroll
    for (int r = 0; r < 4; r++){
      int row = q0 + w*16 + lhi*4 + r;
      int col = head*HD + nf*16 + l15;
      hcat[(size_t)row*CATD + col] = f2us(O[nf][r] / lrow[r]);
    }
  }
}

// ---------------------------------------------------------------------- host
extern "C" void kernel_launch(void* const* d_in, const int* in_sizes, int n_in,
                              void* d_out, int out_size, void* d_ws, size_t ws_size,
                              hipStream_t stream)
{
  const float* hs    = (const float*)d_in[0];
  const float* ehs   = (const float*)d_in[1];
  const float* temb  = (const float*)d_in[2];
  const float* fc    = (const float*)d_in[3];
  const float* wnorm = (const float*)d_in[4];
  const float* bnorm = (const float*)d_in[5];
  const float* wq    = (const float*)d_in[6];
  const float* bq    = (const float*)d_in[7];
  const float* wk    = (const float*)d_in[8];
  const float* bk    = (const float*)d_in[9];
  const float* wv    = (const float*)d_in[10];
  const float* bv    = (const float*)d_in[11];
  const float* nqw   = (const float*)d_in[12];
  const float* nkw   = (const float*)d_in[13];
  const float* wmlp  = (const float*)d_in[14];
  const float* bmlp  = (const float*)d_in[15];
  const float* wout  = (const float*)d_in[16];
  const float* bout  = (const float*)d_in[17];
  float* outp = (float*)d_out;

  char* ws = (char*)d_ws;
  float* emb  = (float*)ws;                               // 36864 B
  float* part = (float*)(ws + 36864);                     // 294912 B
  u16* nx     = (u16*)(ws + 36864 + 294912);
  u16* qkv    = nx  + (size_t)NTOK*HIDDEN;
  u16* hcat   = qkv + (size_t)NTOK*QKVD;
  u16* Wt     = hcat + (size_t)NTOK*CATD;
  float* partial = (float*)nx;  // aliases nx+qkv (dead by out-proj time)

  hipFuncSetAttribute((const void*)gemm8<0>, hipFuncAttributeMaxDynamicSharedMemorySize, 131072);
  hipFuncSetAttribute((const void*)gemm8<1>, hipFuncAttributeMaxDynamicSharedMemorySize, 131072);

  emb_partial<<<dim3(36,8), 256, 0, stream>>>(temb, wnorm, part);
  emb_reduce<<<36, 256, 0, stream>>>(part, bnorm, emb);
  ln_mod<<<NTOK, 256, 0, stream>>>(hs, ehs, emb, nx);

  transpose_w<<<dim3(48,48), 256, 0, stream>>>(wq,   Wt, HIDDEN, HIDDEN, HIDDEN, 0);
  transpose_w<<<dim3(48,48), 256, 0, stream>>>(wk,   Wt, HIDDEN, HIDDEN, HIDDEN, HIDDEN);
  transpose_w<<<dim3(48,48), 256, 0, stream>>>(wv,   Wt, HIDDEN, HIDDEN, HIDDEN, 2*HIDDEN);
  transpose_w<<<dim3(192,48), 256, 0, stream>>>(wmlp, Wt, HIDDEN, MLPD, HIDDEN, QKVD);

  // fused QKV+MLP GEMM: [2304 x 21504], K=3072 (NT=48)
  gemm8<0><<<dim3((FUSEN/256)*MB, 1, 1), 512, 131072, stream>>>(
      nx, HIDDEN, Wt, HIDDEN, HIDDEN, FUSEN, 0,
      bq, bk, bv, bmlp, qkv, hcat, nullptr);

  transpose_w<<<dim3(48,240), 256, 0, stream>>>(wout, Wt, CATD, HIDDEN, CATD, 0);

  qk_post<<<(2*NTOK*HEADS)/4, 256, 0, stream>>>(qkv, nqw, nkw, fc);
  attn_kernel<<<dim3(NTOK/128, HEADS), 512, 0, stream>>>(qkv, hcat);

  // out-proj: split-K=2 (NT=120 each), f32 partials
  gemm8<1><<<dim3((HIDDEN/256)*MB, 1, 2), 512, 131072, stream>>>(
      hcat, CATD, Wt, CATD, CATD/2, HIDDEN, CATD/2,
      nullptr, nullptr, nullptr, nullptr, nullptr, nullptr, partial);

  reduce_out<<<NTOK, 256, 0, stream>>>(partial, bout, emb, hs, ehs, outp);
}